// Round 4
// baseline (1313.380 us; speedup 1.0000x reference)
//
#include <hip/hip_runtime.h>

// Problem constants
#define QD   1280
#define CD   768
#define NH   8
#define NN   2
#define ZZ   2
#define RR   8
#define BFB  16
#define SS   4096
#define DH   160           // QD/NH
#define TT   4             // NN*ZZ
#define OO   32            // NH*TT

typedef __attribute__((ext_vector_type(4))) float f32x4;

// ---------------------------------------------------------------------------
// K1: K/V = lora(ctx3d, W, A, B).  ctx3d[b,t,c] = context[b, t>>1, c] + pe[t&1, c]
// grid (5 jtiles, 4 t, 16 b), 256 thr. Outputs Kf/Vf [16][4][1280] f32.
// ---------------------------------------------------------------------------
__global__ __launch_bounds__(256) void kv_kernel(
    const float* __restrict__ ctx, const float* __restrict__ pe,
    const float* __restrict__ Wk, const float* __restrict__ Ak, const float* __restrict__ Bk,
    const float* __restrict__ Wv, const float* __restrict__ Av, const float* __restrict__ Bv,
    float* __restrict__ Kf, float* __restrict__ Vf)
{
    const int jt = blockIdx.x, t = blockIdx.y, b = blockIdx.z;
    const int n = t >> 1, z = t & 1;
    const int tid = threadIdx.x;
    __shared__ float sctx[CD];
    __shared__ float sa[16];     // a_k[0..7], a_v[8..15]

    for (int c = tid; c < CD; c += 256)
        sctx[c] = ctx[(b * NN + n) * CD + c] + pe[z * CD + c];
    __syncthreads();

    const int wave = tid >> 6, lane = tid & 63;
    for (int q = 0; q < 4; q++) {
        const int idx = wave * 4 + q;                 // 0..15
        const float* Arow = (idx < 8 ? Ak : Av) + (idx & 7) * CD;
        float p = 0.f;
        for (int c = lane; c < CD; c += 64) p += sctx[c] * Arow[c];
        for (int off = 32; off; off >>= 1) p += __shfl_down(p, off);
        if (lane == 0) sa[idx] = p;
    }
    __syncthreads();

    const int j = jt * 256 + tid;
    float accK = 0.f, accV = 0.f;
    {
        f32x4 bk0 = *(const f32x4*)(Bk + j * RR);
        f32x4 bk1 = *(const f32x4*)(Bk + j * RR + 4);
        f32x4 bv0 = *(const f32x4*)(Bv + j * RR);
        f32x4 bv1 = *(const f32x4*)(Bv + j * RR + 4);
#pragma unroll
        for (int r = 0; r < 4; r++) {
            accK += sa[r] * bk0[r] + sa[r + 4] * bk1[r];
            accV += sa[8 + r] * bv0[r] + sa[12 + r] * bv1[r];
        }
    }
    const f32x4* wkrow = (const f32x4*)(Wk + j * CD);
    const f32x4* wvrow = (const f32x4*)(Wv + j * CD);
    for (int c4 = 0; c4 < CD / 4; c4++) {
        f32x4 wk = wkrow[c4], wv = wvrow[c4];
#pragma unroll
        for (int u = 0; u < 4; u++) {
            float xc = sctx[c4 * 4 + u];
            accK += xc * wk[u];
            accV += xc * wv[u];
        }
    }
    Kf[(b * TT + t) * QD + j] = accK;
    Vf[(b * TT + t) * QD + j] = accV;
}

// ---------------------------------------------------------------------------
// K2: P[b][k][ht] = sum_d Wq[h*160+d, k] * Kf[b,t, h*160+d]      (which==0)
//     VW[b][ht][j] = sum_d Vf[b,t, h*160+d] * Wout[j, h*160+d]   (which==1)
// grid (2 which, 32 ht, 16 b), 256 thr.
// ---------------------------------------------------------------------------
__global__ __launch_bounds__(256) void pvw_kernel(
    const float* __restrict__ Wq, const float* __restrict__ Wout,
    const float* __restrict__ Kf, const float* __restrict__ Vf,
    float* __restrict__ P, float* __restrict__ VW)
{
    const int which = blockIdx.x, ht = blockIdx.y, b = blockIdx.z;
    const int h = ht >> 2, t = ht & 3;
    const int tid = threadIdx.x;
    __shared__ float sv[DH];

    if (which == 0) {
        for (int d = tid; d < DH; d += 256) sv[d] = Kf[(b * TT + t) * QD + h * DH + d];
        __syncthreads();
        float acc[5] = {0.f, 0.f, 0.f, 0.f, 0.f};
        for (int d = 0; d < DH; d++) {
            float kd = sv[d];
            const float* wqrow = Wq + (h * DH + d) * QD;
#pragma unroll
            for (int i = 0; i < 5; i++) acc[i] += kd * wqrow[tid + 256 * i];
        }
#pragma unroll
        for (int i = 0; i < 5; i++)
            P[(b * QD + tid + 256 * i) * OO + ht] = acc[i];
    } else {
        for (int d = tid; d < DH; d += 256) sv[d] = Vf[(b * TT + t) * QD + h * DH + d];
        __syncthreads();
        float acc[5] = {0.f, 0.f, 0.f, 0.f, 0.f};
        for (int d4 = 0; d4 < DH / 4; d4++) {
#pragma unroll
            for (int i = 0; i < 5; i++) {
                int j = tid + 256 * i;
                f32x4 w = *(const f32x4*)(Wout + j * QD + h * DH + d4 * 4);
#pragma unroll
                for (int u = 0; u < 4; u++) acc[i] += sv[d4 * 4 + u] * w[u];
            }
        }
#pragma unroll
        for (int i = 0; i < 5; i++)
            VW[(b * OO + ht) * QD + tid + 256 * i] = acc[i];
    }
}

// ---------------------------------------------------------------------------
// K3: scores -> sigmoid -> transmittance -> weights.
//
// Structure (round 4 = round 3 + b*SS fix in the x base address):
//  - NO LDS/SMEM in the main loop: each lane streams its own x row from
//    global (f32x4, sequential; each 64B line fully consumed over 4 iters
//    via L1 -> HBM traffic stays x-read-once).
//  - P comes in as per-lane BROADCAST global_load (vmcnt, in-order,
//    counted waits) -- forced onto the vector path by an opaque VGPR zero
//    in the address. No SMEM in the hot loop.
//  - k-split by 2 for TLP: 512-thr blocks; waves 0-3 do k in [0,640),
//    waves 4-7 do [640,1280) for the same 256 rows -> 2048 waves =
//    2 waves/SIMD. Small padded-LDS reduction + in-lane epilogue.
//
// grid (16 s-tiles of 256 rows, 16 b), 512 thr.
// ---------------------------------------------------------------------------
__global__ __launch_bounds__(512) void scores_kernel(
    const float* __restrict__ x, const float* __restrict__ P,
    float* __restrict__ Wgt)
{
    const int b = blockIdx.y;
    const int tid = threadIdx.x;
    const int w = tid >> 6, lane = tid & 63;
    const int g = w & 3;              // row group 0..3
    const int khalf = w >> 2;         // 0: k in [0,640)   1: k in [640,1280)
    const int row = blockIdx.x * 256 + g * 64 + lane;   // s index within batch
    const float scale = 0.07905694150420949f;   // 1/sqrt(160)

    __shared__ float red[4][64][33];  // 33-pad: (lane*33+o)%32 -> 2 lanes/bank

    // opaque zero in a VGPR: forces P loads onto the vector (vmcnt) path
    int vz;
    asm volatile("v_mov_b32 %0, 0" : "=v"(vz));

    // NOTE: b*SS was missing here in round 3 -> read batch-0 rows for all b.
    const float* xr = x + ((size_t)b * SS + row) * QD + khalf * 640;
    const f32x4* Pv = (const f32x4*)(P + ((size_t)b * QD + khalf * 640) * OO) + vz;

    float acc[32];
#pragma unroll
    for (int o = 0; o < 32; ++o) acc[o] = 0.f;

#pragma unroll 2
    for (int k4 = 0; k4 < 160; ++k4) {
        f32x4 xv = *(const f32x4*)(xr + k4 * 4);
#pragma unroll
        for (int u = 0; u < 4; ++u) {
#pragma unroll
            for (int q = 0; q < 8; ++q) {
                f32x4 pv = Pv[(size_t)(k4 * 4 + u) * 8 + q];
                acc[q * 4 + 0] = fmaf(xv[u], pv[0], acc[q * 4 + 0]);
                acc[q * 4 + 1] = fmaf(xv[u], pv[1], acc[q * 4 + 1]);
                acc[q * 4 + 2] = fmaf(xv[u], pv[2], acc[q * 4 + 2]);
                acc[q * 4 + 3] = fmaf(xv[u], pv[3], acc[q * 4 + 3]);
            }
        }
    }

    // cross-khalf reduction: high waves deposit partials, low waves add.
    if (khalf == 1) {
#pragma unroll
        for (int o = 0; o < 32; ++o) red[g][lane][o] = acc[o];
    }
    __syncthreads();
    if (khalf == 1) return;

#pragma unroll
    for (int o = 0; o < 32; ++o) acc[o] += red[g][lane][o];

    // epilogue: fully in-lane (this lane owns all 32 scores of its row)
    float sig[32];
#pragma unroll
    for (int o = 0; o < 32; ++o) sig[o] = 1.f / (1.f + __expf(-acc[o] * scale));
    float op0 = 0.f;
#pragma unroll
    for (int h = 0; h < 8; ++h) op0 += sig[h * 4 + 0] + sig[h * 4 + 2];
    op0 = fminf(op0 * 0.125f, 1.f);
    const float T1 = 1.f - op0;

    float* Wr = Wgt + ((size_t)b * SS + row) * OO;
#pragma unroll
    for (int q = 0; q < 8; ++q) {
        f32x4 t;
        t[0] = sig[4 * q + 0];
        t[1] = sig[4 * q + 1] * T1;
        t[2] = sig[4 * q + 2];
        t[3] = sig[4 * q + 3] * T1;
        *(f32x4*)(Wr + 4 * q) = t;
    }
}

// ---------------------------------------------------------------------------
// K4: out[b,s,j] = x[b,s,j] + bout[j] + sum_ht w[b,s,ht] * VW[b,ht,j]
// grid (32 s-tiles of 128, 16 b), 320 thr (QD/4 float4 chunks, 16B/lane).
// Thread keeps VW[b][*][4*tid..4*tid+3] in 128 VGPRs.
// ---------------------------------------------------------------------------
__global__ __launch_bounds__(320) void out_kernel(
    const float* __restrict__ x, const float* __restrict__ bout,
    const float* __restrict__ VW, const float* __restrict__ Wgt,
    float* __restrict__ out)
{
    const int b = blockIdx.y;
    const int s0 = blockIdx.x * 128;
    const int tid = threadIdx.x;

    __shared__ float wbuf[8][OO];

    f32x4 vw[32];
    {
        const float* VWb = VW + (size_t)b * OO * QD + 4 * tid;
#pragma unroll
        for (int ht = 0; ht < 32; ht++) vw[ht] = *(const f32x4*)(VWb + ht * QD);
    }
    f32x4 bo = *(const f32x4*)(bout + 4 * tid);

    for (int g = 0; g < 16; g++) {
        __syncthreads();
        if (tid < 256)
            wbuf[tid >> 5][tid & 31] = Wgt[(size_t)(b * SS + s0 + g * 8 + (tid >> 5)) * OO + (tid & 31)];
        __syncthreads();
        for (int row = 0; row < 8; row++) {
            const size_t roff = (size_t)(b * SS + s0 + g * 8 + row) * QD + 4 * tid;
            f32x4 acc = bo + *(const f32x4*)(x + roff);
#pragma unroll
            for (int ht = 0; ht < 32; ht++) {
                float w = wbuf[row][ht];
                acc += w * vw[ht];
            }
            *(f32x4*)(out + roff) = acc;
        }
    }
}

// ---------------------------------------------------------------------------
extern "C" void kernel_launch(void* const* d_in, const int* in_sizes, int n_in,
                              void* d_out, int out_size, void* d_ws, size_t ws_size,
                              hipStream_t stream) {
    const float* x    = (const float*)d_in[0];
    const float* ctx  = (const float*)d_in[1];
    const float* Wq   = (const float*)d_in[2];
    const float* Wk   = (const float*)d_in[3];
    const float* Ak   = (const float*)d_in[4];
    const float* Bk   = (const float*)d_in[5];
    const float* Wv   = (const float*)d_in[6];
    const float* Av   = (const float*)d_in[7];
    const float* Bv   = (const float*)d_in[8];
    const float* pe   = (const float*)d_in[9];
    const float* Wout = (const float*)d_in[10];
    const float* bout = (const float*)d_in[11];
    float* out = (float*)d_out;

    // Workspace layout (floats): Kf 81920 | Vf 81920 | P 655360 | VW 655360 | Wgt 2097152
    float* ws = (float*)d_ws;
    float* Kf = ws;
    float* Vf = ws + 81920;
    float* P  = ws + 163840;
    float* VW = ws + 819200;
    float* Wg = ws + 1474560;   // total 3,571,712 floats = 14.3 MB

    kv_kernel<<<dim3(5, 4, 16), 256, 0, stream>>>(ctx, pe, Wk, Ak, Bk, Wv, Av, Bv, Kf, Vf);
    pvw_kernel<<<dim3(2, 32, 16), 256, 0, stream>>>(Wq, Wout, Kf, Vf, P, VW);
    scores_kernel<<<dim3(16, 16), 512, 0, stream>>>(x, P, Wg);
    out_kernel<<<dim3(32, 16), 320, 0, stream>>>(x, bout, VW, Wg, out);
}

// Round 5
// 963.613 us; speedup vs baseline: 1.3630x; 1.3630x over previous
//
#include <hip/hip_runtime.h>

// Problem constants
#define QD   1280
#define CD   768
#define NH   8
#define NN   2
#define ZZ   2
#define RR   8
#define BFB  16
#define SS   4096
#define DH   160           // QD/NH
#define TT   4             // NN*ZZ
#define OO   32            // NH*TT

typedef __attribute__((ext_vector_type(4))) float f32x4;
typedef __attribute__((ext_vector_type(8))) short short8;   // 8 bf16 = 4 VGPRs (MFMA A/B frag)

// ---------------------------------------------------------------------------
// K1: K/V = lora(ctx3d, W, A, B).  ctx3d[b,t,c] = context[b, t>>1, c] + pe[t&1, c]
// grid (5 jtiles, 4 t, 16 b), 256 thr. Outputs Kf/Vf [16][4][1280] f32.
// ---------------------------------------------------------------------------
__global__ __launch_bounds__(256) void kv_kernel(
    const float* __restrict__ ctx, const float* __restrict__ pe,
    const float* __restrict__ Wk, const float* __restrict__ Ak, const float* __restrict__ Bk,
    const float* __restrict__ Wv, const float* __restrict__ Av, const float* __restrict__ Bv,
    float* __restrict__ Kf, float* __restrict__ Vf)
{
    const int jt = blockIdx.x, t = blockIdx.y, b = blockIdx.z;
    const int n = t >> 1, z = t & 1;
    const int tid = threadIdx.x;
    __shared__ float sctx[CD];
    __shared__ float sa[16];     // a_k[0..7], a_v[8..15]

    for (int c = tid; c < CD; c += 256)
        sctx[c] = ctx[(b * NN + n) * CD + c] + pe[z * CD + c];
    __syncthreads();

    const int wave = tid >> 6, lane = tid & 63;
    for (int q = 0; q < 4; q++) {
        const int idx = wave * 4 + q;                 // 0..15
        const float* Arow = (idx < 8 ? Ak : Av) + (idx & 7) * CD;
        float p = 0.f;
        for (int c = lane; c < CD; c += 64) p += sctx[c] * Arow[c];
        for (int off = 32; off; off >>= 1) p += __shfl_down(p, off);
        if (lane == 0) sa[idx] = p;
    }
    __syncthreads();

    const int j = jt * 256 + tid;
    float accK = 0.f, accV = 0.f;
    {
        f32x4 bk0 = *(const f32x4*)(Bk + j * RR);
        f32x4 bk1 = *(const f32x4*)(Bk + j * RR + 4);
        f32x4 bv0 = *(const f32x4*)(Bv + j * RR);
        f32x4 bv1 = *(const f32x4*)(Bv + j * RR + 4);
#pragma unroll
        for (int r = 0; r < 4; r++) {
            accK += sa[r] * bk0[r] + sa[r + 4] * bk1[r];
            accV += sa[8 + r] * bv0[r] + sa[12 + r] * bv1[r];
        }
    }
    const f32x4* wkrow = (const f32x4*)(Wk + j * CD);
    const f32x4* wvrow = (const f32x4*)(Wv + j * CD);
    for (int c4 = 0; c4 < CD / 4; c4++) {
        f32x4 wk = wkrow[c4], wv = wvrow[c4];
#pragma unroll
        for (int u = 0; u < 4; u++) {
            float xc = sctx[c4 * 4 + u];
            accK += xc * wk[u];
            accV += xc * wv[u];
        }
    }
    Kf[(b * TT + t) * QD + j] = accK;
    Vf[(b * TT + t) * QD + j] = accV;
}

// ---------------------------------------------------------------------------
// K2: P[b][k][ht] = sum_d Wq[h*160+d, k] * Kf[b,t, h*160+d]      (which==0)
//     VW[b][ht][j] = sum_d Vf[b,t, h*160+d] * Wout[j, h*160+d]   (which==1)
// grid (2 which, 32 ht, 16 b), 256 thr.
// ---------------------------------------------------------------------------
__global__ __launch_bounds__(256) void pvw_kernel(
    const float* __restrict__ Wq, const float* __restrict__ Wout,
    const float* __restrict__ Kf, const float* __restrict__ Vf,
    float* __restrict__ P, float* __restrict__ VW)
{
    const int which = blockIdx.x, ht = blockIdx.y, b = blockIdx.z;
    const int h = ht >> 2, t = ht & 3;
    const int tid = threadIdx.x;
    __shared__ float sv[DH];

    if (which == 0) {
        for (int d = tid; d < DH; d += 256) sv[d] = Kf[(b * TT + t) * QD + h * DH + d];
        __syncthreads();
        float acc[5] = {0.f, 0.f, 0.f, 0.f, 0.f};
        for (int d = 0; d < DH; d++) {
            float kd = sv[d];
            const float* wqrow = Wq + (h * DH + d) * QD;
#pragma unroll
            for (int i = 0; i < 5; i++) acc[i] += kd * wqrow[tid + 256 * i];
        }
#pragma unroll
        for (int i = 0; i < 5; i++)
            P[(b * QD + tid + 256 * i) * OO + ht] = acc[i];
    } else {
        for (int d = tid; d < DH; d += 256) sv[d] = Vf[(b * TT + t) * QD + h * DH + d];
        __syncthreads();
        float acc[5] = {0.f, 0.f, 0.f, 0.f, 0.f};
        for (int d4 = 0; d4 < DH / 4; d4++) {
#pragma unroll
            for (int i = 0; i < 5; i++) {
                int j = tid + 256 * i;
                f32x4 w = *(const f32x4*)(Wout + j * QD + h * DH + d4 * 4);
#pragma unroll
                for (int u = 0; u < 4; u++) acc[i] += sv[d4 * 4 + u] * w[u];
            }
        }
#pragma unroll
        for (int i = 0; i < 5; i++)
            VW[(b * OO + ht) * QD + tid + 256 * i] = acc[i];
    }
}

// ---------------------------------------------------------------------------
// K2b (new): pre-pack P (f32 [b][k][o]) into bf16 MFMA B-fragments.
// Pfrag[b][ks][nt][lane][j] where k = ks*32 + (lane>>4)*8 + j, o = nt*16+(lane&15).
// Pairs (j even, j+1) packed with v_cvt_pk_bf16_f32 — SAME pairing as the
// A-side in scores_kernel, so the dot pairing is lo/hi-convention-invariant.
// grid (80 = ks*2+nt, 16 b), 64 thr.
// ---------------------------------------------------------------------------
__global__ __launch_bounds__(64) void pfrag_kernel(
    const float* __restrict__ P, unsigned* __restrict__ Pfrag)
{
    const int ksnt = blockIdx.x;          // 0..79
    const int b = blockIdx.y;
    const int ks = ksnt >> 1, nt = ksnt & 1;
    const int l = threadIdx.x;
    const int k0 = ks * 32 + (l >> 4) * 8;
    const int o  = nt * 16 + (l & 15);

    const float* Pb = P + ((size_t)b * QD + k0) * OO + o;
    float v[8];
#pragma unroll
    for (int j = 0; j < 8; j++) v[j] = Pb[j * OO];

    unsigned d[4];
#pragma unroll
    for (int i = 0; i < 4; i++)
        asm("v_cvt_pk_bf16_f32 %0, %1, %2" : "=v"(d[i]) : "v"(v[2 * i]), "v"(v[2 * i + 1]));

    unsigned* dst = Pfrag + ((size_t)(b * 80 + ksnt) * 64 + l) * 4;
    dst[0] = d[0]; dst[1] = d[1]; dst[2] = d[2]; dst[3] = d[3];
}

// ---------------------------------------------------------------------------
// K3: scores via bf16 MFMA (round-5 rewrite).
//
// Why: all three VALU formulations hit a broadcast wall — one operand must
// reach 32 lanes through LDS-return-bus (236us), SMEM-lgkm-mix (254us) or
// VMEM-broadcast (525us, VGPR-starved). mfma_f32_16x16x32_bf16 does the
// 32-way broadcast inside the matrix pipe: x passes through VGPRs once,
// P-fragments are 16B/lane coalesced loads, no LDS at all.
//
// Wave = 32 rows (2 M-tiles) x 32 o (2 N-tiles), K=1280 in 40 steps.
// A-frag: lane l -> row (l&15), k = kb + (l>>4)*8 + j  (cvt_pk from f32 x).
// B-frag: pre-packed by pfrag_kernel (same j pairing).
// C: col = lane&15 (=o), row = (lane>>4)*4 + reg   [m89 layout].
// Epilogue in-register; opacity via 16-lane __shfl_xor reduce over even-o.
//
// grid (32 s-tiles of 128 rows, 16 b), 256 thr (4 waves). 2048 waves = 2/SIMD.
// ---------------------------------------------------------------------------
__global__ __launch_bounds__(256, 2) void scores_kernel(
    const float* __restrict__ x, const unsigned* __restrict__ Pfrag,
    float* __restrict__ Wgt)
{
    const int b = blockIdx.y;
    const int tid = threadIdx.x;
    const int w = tid >> 6, l = tid & 63;
    const int lg = l >> 4, lo16 = l & 15;
    const int rowbase = blockIdx.x * 128 + w * 32;      // per-batch s of this wave
    const float scale = 0.07905694150420949f;           // 1/sqrt(160)

    f32x4 acc[2][2];
#pragma unroll
    for (int m = 0; m < 2; ++m)
#pragma unroll
        for (int nt = 0; nt < 2; ++nt)
            acc[m][nt] = (f32x4){0.f, 0.f, 0.f, 0.f};

    const float* xb = x + ((size_t)b * SS + rowbase) * QD;
    const float* xr0 = xb + (size_t)lo16 * QD;          // m=0 row for this lane
    const float* xr1 = xb + (size_t)(16 + lo16) * QD;   // m=1 row
    const unsigned* Pfb = Pfrag + (size_t)b * 80 * 256 + (size_t)l * 4;

    union U { unsigned u[4]; short8 s; };

    for (int ks = 0; ks < 40; ++ks) {
        const int kb = ks * 32 + lg * 8;
        f32x4 x00 = *(const f32x4*)(xr0 + kb);
        f32x4 x01 = *(const f32x4*)(xr0 + kb + 4);
        f32x4 x10 = *(const f32x4*)(xr1 + kb);
        f32x4 x11 = *(const f32x4*)(xr1 + kb + 4);
        short8 bf0 = *(const short8*)(Pfb + (size_t)(ks * 2 + 0) * 256);
        short8 bf1 = *(const short8*)(Pfb + (size_t)(ks * 2 + 1) * 256);

        U a0, a1;
        asm("v_cvt_pk_bf16_f32 %0, %1, %2" : "=v"(a0.u[0]) : "v"(x00[0]), "v"(x00[1]));
        asm("v_cvt_pk_bf16_f32 %0, %1, %2" : "=v"(a0.u[1]) : "v"(x00[2]), "v"(x00[3]));
        asm("v_cvt_pk_bf16_f32 %0, %1, %2" : "=v"(a0.u[2]) : "v"(x01[0]), "v"(x01[1]));
        asm("v_cvt_pk_bf16_f32 %0, %1, %2" : "=v"(a0.u[3]) : "v"(x01[2]), "v"(x01[3]));
        asm("v_cvt_pk_bf16_f32 %0, %1, %2" : "=v"(a1.u[0]) : "v"(x10[0]), "v"(x10[1]));
        asm("v_cvt_pk_bf16_f32 %0, %1, %2" : "=v"(a1.u[1]) : "v"(x10[2]), "v"(x10[3]));
        asm("v_cvt_pk_bf16_f32 %0, %1, %2" : "=v"(a1.u[2]) : "v"(x11[0]), "v"(x11[1]));
        asm("v_cvt_pk_bf16_f32 %0, %1, %2" : "=v"(a1.u[3]) : "v"(x11[2]), "v"(x11[3]));

        acc[0][0] = __builtin_amdgcn_mfma_f32_16x16x32_bf16(a0.s, bf0, acc[0][0], 0, 0, 0);
        acc[0][1] = __builtin_amdgcn_mfma_f32_16x16x32_bf16(a0.s, bf1, acc[0][1], 0, 0, 0);
        acc[1][0] = __builtin_amdgcn_mfma_f32_16x16x32_bf16(a1.s, bf0, acc[1][0], 0, 0, 0);
        acc[1][1] = __builtin_amdgcn_mfma_f32_16x16x32_bf16(a1.s, bf1, acc[1][1], 0, 0, 0);
    }

    // epilogue: lane holds rows (lg*4 + r) of each M-tile at o = lo16 and lo16+16.
    // z = o&1 = l&1 (same parity for both N-tiles). op0 = (1/8) * sum over the
    // 16 even-o sigmas; reduce across the 16-lane group via shfl_xor.
#pragma unroll
    for (int m = 0; m < 2; ++m) {
#pragma unroll
        for (int r = 0; r < 4; ++r) {
            float s0 = 1.f / (1.f + __expf(-acc[m][0][r] * scale));
            float s1 = 1.f / (1.f + __expf(-acc[m][1][r] * scale));
            float contrib = ((l & 1) == 0) ? (s0 + s1) : 0.f;
            contrib += __shfl_xor(contrib, 1);
            contrib += __shfl_xor(contrib, 2);
            contrib += __shfl_xor(contrib, 4);
            contrib += __shfl_xor(contrib, 8);
            float op0 = fminf(contrib * 0.125f, 1.f);
            float t1 = (l & 1) ? (1.f - op0) : 1.f;
            const int R = rowbase + m * 16 + lg * 4 + r;
            float* Wr = Wgt + ((size_t)b * SS + R) * OO;
            Wr[lo16]      = s0 * t1;
            Wr[lo16 + 16] = s1 * t1;
        }
    }
}

// ---------------------------------------------------------------------------
// K4: out[b,s,j] = x[b,s,j] + bout[j] + sum_ht w[b,s,ht] * VW[b,ht,j]
// grid (32 s-tiles of 128, 16 b), 320 thr (QD/4 float4 chunks, 16B/lane).
// Thread keeps VW[b][*][4*tid..4*tid+3] in 128 VGPRs.
// ---------------------------------------------------------------------------
__global__ __launch_bounds__(320) void out_kernel(
    const float* __restrict__ x, const float* __restrict__ bout,
    const float* __restrict__ VW, const float* __restrict__ Wgt,
    float* __restrict__ out)
{
    const int b = blockIdx.y;
    const int s0 = blockIdx.x * 128;
    const int tid = threadIdx.x;

    __shared__ float wbuf[8][OO];

    f32x4 vw[32];
    {
        const float* VWb = VW + (size_t)b * OO * QD + 4 * tid;
#pragma unroll
        for (int ht = 0; ht < 32; ht++) vw[ht] = *(const f32x4*)(VWb + ht * QD);
    }
    f32x4 bo = *(const f32x4*)(bout + 4 * tid);

    for (int g = 0; g < 16; g++) {
        __syncthreads();
        if (tid < 256)
            wbuf[tid >> 5][tid & 31] = Wgt[(size_t)(b * SS + s0 + g * 8 + (tid >> 5)) * OO + (tid & 31)];
        __syncthreads();
        for (int row = 0; row < 8; row++) {
            const size_t roff = (size_t)(b * SS + s0 + g * 8 + row) * QD + 4 * tid;
            f32x4 acc = bo + *(const f32x4*)(x + roff);
#pragma unroll
            for (int ht = 0; ht < 32; ht++) {
                float w = wbuf[row][ht];
                acc += w * vw[ht];
            }
            *(f32x4*)(out + roff) = acc;
        }
    }
}

// ---------------------------------------------------------------------------
extern "C" void kernel_launch(void* const* d_in, const int* in_sizes, int n_in,
                              void* d_out, int out_size, void* d_ws, size_t ws_size,
                              hipStream_t stream) {
    const float* x    = (const float*)d_in[0];
    const float* ctx  = (const float*)d_in[1];
    const float* Wq   = (const float*)d_in[2];
    const float* Wk   = (const float*)d_in[3];
    const float* Ak   = (const float*)d_in[4];
    const float* Bk   = (const float*)d_in[5];
    const float* Wv   = (const float*)d_in[6];
    const float* Av   = (const float*)d_in[7];
    const float* Bv   = (const float*)d_in[8];
    const float* pe   = (const float*)d_in[9];
    const float* Wout = (const float*)d_in[10];
    const float* bout = (const float*)d_in[11];
    float* out = (float*)d_out;

    // Workspace layout (floats):
    // Kf 81920 | Vf 81920 | P 655360 | VW 655360 | Wgt 2097152 | Pfrag 327680
    float* ws = (float*)d_ws;
    float* Kf = ws;
    float* Vf = ws + 81920;
    float* P  = ws + 163840;
    float* VW = ws + 819200;
    float* Wg = ws + 1474560;
    unsigned* Pfrag = (unsigned*)(ws + 3571712);   // total 3,899,392 floats = 15.6 MB

    kv_kernel<<<dim3(5, 4, 16), 256, 0, stream>>>(ctx, pe, Wk, Ak, Bk, Wv, Av, Bv, Kf, Vf);
    pvw_kernel<<<dim3(2, 32, 16), 256, 0, stream>>>(Wq, Wout, Kf, Vf, P, VW);
    pfrag_kernel<<<dim3(80, 16), 64, 0, stream>>>(P, Pfrag);
    scores_kernel<<<dim3(32, 16), 256, 0, stream>>>(x, Pfrag, Wg);
    out_kernel<<<dim3(32, 16), 320, 0, stream>>>(x, bout, VW, Wg, out);
}

// Round 6
// 940.460 us; speedup vs baseline: 1.3965x; 1.0246x over previous
//
#include <hip/hip_runtime.h>

// Problem constants
#define QD   1280
#define CD   768
#define NH   8
#define NN   2
#define ZZ   2
#define RR   8
#define BFB  16
#define SS   4096
#define DH   160           // QD/NH
#define TT   4             // NN*ZZ
#define OO   32            // NH*TT

typedef __attribute__((ext_vector_type(4))) float f32x4;
typedef __attribute__((ext_vector_type(8))) short short8;   // 8 bf16 = 4 VGPRs (MFMA A/B frag)

// ---------------------------------------------------------------------------
// K1: K/V = lora(ctx3d, W, A, B).  ctx3d[b,t,c] = context[b, t>>1, c] + pe[t&1, c]
// grid (5 jtiles, 4 t, 16 b), 256 thr. Outputs Kf/Vf [16][4][1280] f32.
// ---------------------------------------------------------------------------
__global__ __launch_bounds__(256) void kv_kernel(
    const float* __restrict__ ctx, const float* __restrict__ pe,
    const float* __restrict__ Wk, const float* __restrict__ Ak, const float* __restrict__ Bk,
    const float* __restrict__ Wv, const float* __restrict__ Av, const float* __restrict__ Bv,
    float* __restrict__ Kf, float* __restrict__ Vf)
{
    const int jt = blockIdx.x, t = blockIdx.y, b = blockIdx.z;
    const int n = t >> 1, z = t & 1;
    const int tid = threadIdx.x;
    __shared__ float sctx[CD];
    __shared__ float sa[16];     // a_k[0..7], a_v[8..15]

    for (int c = tid; c < CD; c += 256)
        sctx[c] = ctx[(b * NN + n) * CD + c] + pe[z * CD + c];
    __syncthreads();

    const int wave = tid >> 6, lane = tid & 63;
    for (int q = 0; q < 4; q++) {
        const int idx = wave * 4 + q;                 // 0..15
        const float* Arow = (idx < 8 ? Ak : Av) + (idx & 7) * CD;
        float p = 0.f;
        for (int c = lane; c < CD; c += 64) p += sctx[c] * Arow[c];
        for (int off = 32; off; off >>= 1) p += __shfl_down(p, off);
        if (lane == 0) sa[idx] = p;
    }
    __syncthreads();

    const int j = jt * 256 + tid;
    float accK = 0.f, accV = 0.f;
    {
        f32x4 bk0 = *(const f32x4*)(Bk + j * RR);
        f32x4 bk1 = *(const f32x4*)(Bk + j * RR + 4);
        f32x4 bv0 = *(const f32x4*)(Bv + j * RR);
        f32x4 bv1 = *(const f32x4*)(Bv + j * RR + 4);
#pragma unroll
        for (int r = 0; r < 4; r++) {
            accK += sa[r] * bk0[r] + sa[r + 4] * bk1[r];
            accV += sa[8 + r] * bv0[r] + sa[12 + r] * bv1[r];
        }
    }
    const f32x4* wkrow = (const f32x4*)(Wk + j * CD);
    const f32x4* wvrow = (const f32x4*)(Wv + j * CD);
    for (int c4 = 0; c4 < CD / 4; c4++) {
        f32x4 wk = wkrow[c4], wv = wvrow[c4];
#pragma unroll
        for (int u = 0; u < 4; u++) {
            float xc = sctx[c4 * 4 + u];
            accK += xc * wk[u];
            accV += xc * wv[u];
        }
    }
    Kf[(b * TT + t) * QD + j] = accK;
    Vf[(b * TT + t) * QD + j] = accV;
}

// ---------------------------------------------------------------------------
// K2: P[b][k][ht] = sum_d Wq[h*160+d, k] * Kf[b,t, h*160+d]      (which==0)
//     VW[b][ht][j] = sum_d Vf[b,t, h*160+d] * Wout[j, h*160+d]   (which==1)
// grid (2 which, 32 ht, 16 b), 256 thr.
// ---------------------------------------------------------------------------
__global__ __launch_bounds__(256) void pvw_kernel(
    const float* __restrict__ Wq, const float* __restrict__ Wout,
    const float* __restrict__ Kf, const float* __restrict__ Vf,
    float* __restrict__ P, float* __restrict__ VW)
{
    const int which = blockIdx.x, ht = blockIdx.y, b = blockIdx.z;
    const int h = ht >> 2, t = ht & 3;
    const int tid = threadIdx.x;
    __shared__ float sv[DH];

    if (which == 0) {
        for (int d = tid; d < DH; d += 256) sv[d] = Kf[(b * TT + t) * QD + h * DH + d];
        __syncthreads();
        float acc[5] = {0.f, 0.f, 0.f, 0.f, 0.f};
        for (int d = 0; d < DH; d++) {
            float kd = sv[d];
            const float* wqrow = Wq + (h * DH + d) * QD;
#pragma unroll
            for (int i = 0; i < 5; i++) acc[i] += kd * wqrow[tid + 256 * i];
        }
#pragma unroll
        for (int i = 0; i < 5; i++)
            P[(b * QD + tid + 256 * i) * OO + ht] = acc[i];
    } else {
        for (int d = tid; d < DH; d += 256) sv[d] = Vf[(b * TT + t) * QD + h * DH + d];
        __syncthreads();
        float acc[5] = {0.f, 0.f, 0.f, 0.f, 0.f};
        for (int d4 = 0; d4 < DH / 4; d4++) {
#pragma unroll
            for (int i = 0; i < 5; i++) {
                int j = tid + 256 * i;
                f32x4 w = *(const f32x4*)(Wout + j * QD + h * DH + d4 * 4);
#pragma unroll
                for (int u = 0; u < 4; u++) acc[i] += sv[d4 * 4 + u] * w[u];
            }
        }
#pragma unroll
        for (int i = 0; i < 5; i++)
            VW[(b * OO + ht) * QD + tid + 256 * i] = acc[i];
    }
}

// ---------------------------------------------------------------------------
// K2b: pre-pack P (f32 [b][k][o]) into bf16 MFMA B-fragments.
// Pfrag[b][ks][nt][lane][j] where k = ks*32 + (lane>>4)*8 + j, o = nt*16+(lane&15).
// Pairs (j even, j+1) packed with v_cvt_pk_bf16_f32 — SAME pairing as the
// A-side in scores_kernel, so the dot pairing is lo/hi-convention-invariant.
// grid (80 = ks*2+nt, 16 b), 64 thr.
// ---------------------------------------------------------------------------
__global__ __launch_bounds__(64) void pfrag_kernel(
    const float* __restrict__ P, unsigned* __restrict__ Pfrag)
{
    const int ksnt = blockIdx.x;          // 0..79
    const int b = blockIdx.y;
    const int ks = ksnt >> 1, nt = ksnt & 1;
    const int l = threadIdx.x;
    const int k0 = ks * 32 + (l >> 4) * 8;
    const int o  = nt * 16 + (l & 15);

    const float* Pb = P + ((size_t)b * QD + k0) * OO + o;
    float v[8];
#pragma unroll
    for (int j = 0; j < 8; j++) v[j] = Pb[j * OO];

    unsigned d[4];
#pragma unroll
    for (int i = 0; i < 4; i++)
        asm("v_cvt_pk_bf16_f32 %0, %1, %2" : "=v"(d[i]) : "v"(v[2 * i]), "v"(v[2 * i + 1]));

    unsigned* dst = Pfrag + ((size_t)(b * 80 + ksnt) * 64 + l) * 4;
    dst[0] = d[0]; dst[1] = d[1]; dst[2] = d[2]; dst[3] = d[3];
}

// ---------------------------------------------------------------------------
// K3: scores via bf16 MFMA.
//
// Round-6 change: 1 M-tile (16 rows) x 2 N-tiles per wave (was 2x2).
// 4096 waves = 4 waves/SIMD (was 2) -> double TLP to hide the HBM-latency
// of the per-lane-row A-operand loads. Per-iter VMEM drops 6 -> 4 instrs;
// VGPR ~50 so occupancy is register-unconstrained. B-frags are L2-resident.
//
// A-frag: lane l -> row (l&15), k = kb + (l>>4)*8 + j  (cvt_pk from f32 x).
// B-frag: pre-packed by pfrag_kernel (same j pairing).
// C: col = lane&15 (=o), row = (lane>>4)*4 + reg   [m89 layout].
// Epilogue in-register; opacity via 16-lane __shfl_xor reduce over even-o.
//
// grid (64 s-tiles of 64 rows, 16 b), 256 thr (4 waves x 16 rows).
// ---------------------------------------------------------------------------
__global__ __launch_bounds__(256) void scores_kernel(
    const float* __restrict__ x, const unsigned* __restrict__ Pfrag,
    float* __restrict__ Wgt)
{
    const int b = blockIdx.y;
    const int tid = threadIdx.x;
    const int w = tid >> 6, l = tid & 63;
    const int lg = l >> 4, lo16 = l & 15;
    const int rowbase = blockIdx.x * 64 + w * 16;       // per-batch s of this wave
    const float scale = 0.07905694150420949f;           // 1/sqrt(160)

    f32x4 acc0 = (f32x4){0.f, 0.f, 0.f, 0.f};
    f32x4 acc1 = (f32x4){0.f, 0.f, 0.f, 0.f};

    const float* xr0 = x + ((size_t)b * SS + rowbase + lo16) * QD;   // this lane's row
    const unsigned* Pfb = Pfrag + (size_t)b * 80 * 256 + (size_t)l * 4;

    union U { unsigned u[4]; short8 s; };

    for (int ks = 0; ks < 40; ++ks) {
        const int kb = ks * 32 + lg * 8;
        f32x4 x00 = *(const f32x4*)(xr0 + kb);
        f32x4 x01 = *(const f32x4*)(xr0 + kb + 4);
        short8 bf0 = *(const short8*)(Pfb + (size_t)(ks * 2 + 0) * 256);
        short8 bf1 = *(const short8*)(Pfb + (size_t)(ks * 2 + 1) * 256);

        U a0;
        asm("v_cvt_pk_bf16_f32 %0, %1, %2" : "=v"(a0.u[0]) : "v"(x00[0]), "v"(x00[1]));
        asm("v_cvt_pk_bf16_f32 %0, %1, %2" : "=v"(a0.u[1]) : "v"(x00[2]), "v"(x00[3]));
        asm("v_cvt_pk_bf16_f32 %0, %1, %2" : "=v"(a0.u[2]) : "v"(x01[0]), "v"(x01[1]));
        asm("v_cvt_pk_bf16_f32 %0, %1, %2" : "=v"(a0.u[3]) : "v"(x01[2]), "v"(x01[3]));

        acc0 = __builtin_amdgcn_mfma_f32_16x16x32_bf16(a0.s, bf0, acc0, 0, 0, 0);
        acc1 = __builtin_amdgcn_mfma_f32_16x16x32_bf16(a0.s, bf1, acc1, 0, 0, 0);
    }

    // epilogue: lane holds rows (rowbase + lg*4 + r) at o = lo16 and lo16+16.
    // z = o&1 = l&1 (same parity for both N-tiles). op0 = (1/8) * sum of the
    // 16 even-o sigmas; reduce across the 16-lane group via shfl_xor (masks
    // 1,2,4,8 stay within the lg group, which owns these 4 rows).
#pragma unroll
    for (int r = 0; r < 4; ++r) {
        float s0v = 1.f / (1.f + __expf(-acc0[r] * scale));
        float s1v = 1.f / (1.f + __expf(-acc1[r] * scale));
        float contrib = ((l & 1) == 0) ? (s0v + s1v) : 0.f;
        contrib += __shfl_xor(contrib, 1);
        contrib += __shfl_xor(contrib, 2);
        contrib += __shfl_xor(contrib, 4);
        contrib += __shfl_xor(contrib, 8);
        float op0 = fminf(contrib * 0.125f, 1.f);
        float t1 = (l & 1) ? (1.f - op0) : 1.f;
        const int R = rowbase + lg * 4 + r;
        float* Wr = Wgt + ((size_t)b * SS + R) * OO;
        Wr[lo16]      = s0v * t1;
        Wr[lo16 + 16] = s1v * t1;
    }
}

// ---------------------------------------------------------------------------
// K4: out[b,s,j] = x[b,s,j] + bout[j] + sum_ht w[b,s,ht] * VW[b,ht,j]
//
// Round-6 change: weights Wgt[row][.] are BLOCK-UNIFORM -> read them through
// a uniform address so the compiler emits s_load (SMEM pipe): no LDS, no
// __syncthreads, no broadcast waste. lgkm counter is SMEM-only here (no
// ds_read mixing). Grid doubled to 1024 blocks (4/CU); rows unrolled x2 so
// two rows' x-loads / s_loads are in flight; the 4 components of the f32x4
// accumulator are independent FMA chains.
//
// grid (64 s-tiles of 64, 16 b), 320 thr (QD/4 float4 chunks, 16B/lane).
// Thread keeps VW[b][*][4*tid..4*tid+3] in 128 VGPRs.
// ---------------------------------------------------------------------------
__global__ __launch_bounds__(320) void out_kernel(
    const float* __restrict__ x, const float* __restrict__ bout,
    const float* __restrict__ VW, const float* __restrict__ Wgt,
    float* __restrict__ out)
{
    const int b = blockIdx.y;
    const int s0 = blockIdx.x * 64;
    const int tid = threadIdx.x;

    f32x4 vw[32];
    {
        const float* VWb = VW + (size_t)b * OO * QD + 4 * tid;
#pragma unroll
        for (int ht = 0; ht < 32; ht++) vw[ht] = *(const f32x4*)(VWb + ht * QD);
    }
    f32x4 bo = *(const f32x4*)(bout + 4 * tid);

    const size_t base = ((size_t)b * SS + s0) * QD + 4 * tid;
    const float* wg0 = Wgt + ((size_t)b * SS + s0) * OO;   // uniform base

#pragma unroll 2
    for (int row = 0; row < 64; ++row) {
        f32x4 acc = bo + *(const f32x4*)(x + base + (size_t)row * QD);
        const float* wr = wg0 + row * OO;                  // uniform -> s_load
#pragma unroll
        for (int ht = 0; ht < 32; ht++) {
            float wv_ = wr[ht];
            acc += wv_ * vw[ht];
        }
        *(f32x4*)(out + base + (size_t)row * QD) = acc;
    }
}

// ---------------------------------------------------------------------------
extern "C" void kernel_launch(void* const* d_in, const int* in_sizes, int n_in,
                              void* d_out, int out_size, void* d_ws, size_t ws_size,
                              hipStream_t stream) {
    const float* x    = (const float*)d_in[0];
    const float* ctx  = (const float*)d_in[1];
    const float* Wq   = (const float*)d_in[2];
    const float* Wk   = (const float*)d_in[3];
    const float* Ak   = (const float*)d_in[4];
    const float* Bk   = (const float*)d_in[5];
    const float* Wv   = (const float*)d_in[6];
    const float* Av   = (const float*)d_in[7];
    const float* Bv   = (const float*)d_in[8];
    const float* pe   = (const float*)d_in[9];
    const float* Wout = (const float*)d_in[10];
    const float* bout = (const float*)d_in[11];
    float* out = (float*)d_out;

    // Workspace layout (floats):
    // Kf 81920 | Vf 81920 | P 655360 | VW 655360 | Wgt 2097152 | Pfrag 327680
    float* ws = (float*)d_ws;
    float* Kf = ws;
    float* Vf = ws + 81920;
    float* P  = ws + 163840;
    float* VW = ws + 819200;
    float* Wg = ws + 1474560;
    unsigned* Pfrag = (unsigned*)(ws + 3571712);   // total 3,899,392 floats = 15.6 MB

    kv_kernel<<<dim3(5, 4, 16), 256, 0, stream>>>(ctx, pe, Wk, Ak, Bk, Wv, Av, Bv, Kf, Vf);
    pvw_kernel<<<dim3(2, 32, 16), 256, 0, stream>>>(Wq, Wout, Kf, Vf, P, VW);
    pfrag_kernel<<<dim3(80, 16), 64, 0, stream>>>(P, Pfrag);
    scores_kernel<<<dim3(64, 16), 256, 0, stream>>>(x, Pfrag, Wg);
    out_kernel<<<dim3(64, 16), 320, 0, stream>>>(x, bout, VW, Wg, out);
}

// Round 7
// 847.660 us; speedup vs baseline: 1.5494x; 1.1095x over previous
//
#include <hip/hip_runtime.h>

// Problem constants
#define QD   1280
#define CD   768
#define NH   8
#define NN   2
#define ZZ   2
#define RR   8
#define BFB  16
#define SS   4096
#define DH   160           // QD/NH
#define TT   4             // NN*ZZ
#define OO   32            // NH*TT

typedef __attribute__((ext_vector_type(4))) float f32x4;
typedef __attribute__((ext_vector_type(8))) short short8;   // 8 bf16 = 4 VGPRs (MFMA A/B frag)

// ---------------------------------------------------------------------------
// K1: K/V = lora(ctx3d, W, A, B).  ctx3d[b,t,c] = context[b, t>>1, c] + pe[t&1, c]
// grid (5 jtiles, 4 t, 16 b), 256 thr. Outputs Kf/Vf [16][4][1280] f32.
// ---------------------------------------------------------------------------
__global__ __launch_bounds__(256) void kv_kernel(
    const float* __restrict__ ctx, const float* __restrict__ pe,
    const float* __restrict__ Wk, const float* __restrict__ Ak, const float* __restrict__ Bk,
    const float* __restrict__ Wv, const float* __restrict__ Av, const float* __restrict__ Bv,
    float* __restrict__ Kf, float* __restrict__ Vf)
{
    const int jt = blockIdx.x, t = blockIdx.y, b = blockIdx.z;
    const int n = t >> 1, z = t & 1;
    const int tid = threadIdx.x;
    __shared__ float sctx[CD];
    __shared__ float sa[16];     // a_k[0..7], a_v[8..15]

    for (int c = tid; c < CD; c += 256)
        sctx[c] = ctx[(b * NN + n) * CD + c] + pe[z * CD + c];
    __syncthreads();

    const int wave = tid >> 6, lane = tid & 63;
    for (int q = 0; q < 4; q++) {
        const int idx = wave * 4 + q;                 // 0..15
        const float* Arow = (idx < 8 ? Ak : Av) + (idx & 7) * CD;
        float p = 0.f;
        for (int c = lane; c < CD; c += 64) p += sctx[c] * Arow[c];
        for (int off = 32; off; off >>= 1) p += __shfl_down(p, off);
        if (lane == 0) sa[idx] = p;
    }
    __syncthreads();

    const int j = jt * 256 + tid;
    float accK = 0.f, accV = 0.f;
    {
        f32x4 bk0 = *(const f32x4*)(Bk + j * RR);
        f32x4 bk1 = *(const f32x4*)(Bk + j * RR + 4);
        f32x4 bv0 = *(const f32x4*)(Bv + j * RR);
        f32x4 bv1 = *(const f32x4*)(Bv + j * RR + 4);
#pragma unroll
        for (int r = 0; r < 4; r++) {
            accK += sa[r] * bk0[r] + sa[r + 4] * bk1[r];
            accV += sa[8 + r] * bv0[r] + sa[12 + r] * bv1[r];
        }
    }
    const f32x4* wkrow = (const f32x4*)(Wk + j * CD);
    const f32x4* wvrow = (const f32x4*)(Wv + j * CD);
    for (int c4 = 0; c4 < CD / 4; c4++) {
        f32x4 wk = wkrow[c4], wv = wvrow[c4];
#pragma unroll
        for (int u = 0; u < 4; u++) {
            float xc = sctx[c4 * 4 + u];
            accK += xc * wk[u];
            accV += xc * wv[u];
        }
    }
    Kf[(b * TT + t) * QD + j] = accK;
    Vf[(b * TT + t) * QD + j] = accV;
}

// ---------------------------------------------------------------------------
// K2: P[b][k][h*4+t] and VW[b][ht][j], t-batched (round-7).
//
// Round-7 change: each block computes ALL 4 t for its (which, h, b) ->
// Wq/Wout slices read once per (h,b) instead of once per (ht,b): weight
// re-read traffic 840 -> 210 MB. Bonus: P-store becomes one contiguous
// f32x4 per j (was 4B at 128B stride). Grid (2 which, 8 h, 16 b), 256 thr.
// d-loop is only 160 iters, so even at 1 block/CU the wall time is small.
// ---------------------------------------------------------------------------
__global__ __launch_bounds__(256) void pvw_kernel(
    const float* __restrict__ Wq, const float* __restrict__ Wout,
    const float* __restrict__ Kf, const float* __restrict__ Vf,
    float* __restrict__ P, float* __restrict__ VW)
{
    const int which = blockIdx.x, h = blockIdx.y, b = blockIdx.z;
    const int tid = threadIdx.x;
    __shared__ float sv[TT][DH];

    const float* src = (which == 0 ? Kf : Vf);
    for (int e = tid; e < TT * DH; e += 256) {
        int t = e / DH, d = e % DH;
        sv[t][d] = src[(b * TT + t) * QD + h * DH + d];
    }
    __syncthreads();

    if (which == 0) {
        float acc[5][4];
#pragma unroll
        for (int i = 0; i < 5; i++)
#pragma unroll
            for (int t = 0; t < 4; t++) acc[i][t] = 0.f;

#pragma unroll 2
        for (int d = 0; d < DH; d++) {
            const float* wqrow = Wq + (h * DH + d) * QD;
            float wq[5];
#pragma unroll
            for (int i = 0; i < 5; i++) wq[i] = wqrow[tid + 256 * i];
#pragma unroll
            for (int i = 0; i < 5; i++)
#pragma unroll
                for (int t = 0; t < 4; t++)
                    acc[i][t] = fmaf(sv[t][d], wq[i], acc[i][t]);
        }
#pragma unroll
        for (int i = 0; i < 5; i++) {
            int j = tid + 256 * i;
            f32x4 v = {acc[i][0], acc[i][1], acc[i][2], acc[i][3]};
            *(f32x4*)(P + ((size_t)(b * QD + j)) * OO + h * 4) = v;
        }
    } else {
        float acc[5][4];
#pragma unroll
        for (int i = 0; i < 5; i++)
#pragma unroll
            for (int t = 0; t < 4; t++) acc[i][t] = 0.f;

        for (int d4 = 0; d4 < DH / 4; d4++) {
#pragma unroll
            for (int i = 0; i < 5; i++) {
                int j = tid + 256 * i;
                f32x4 w = *(const f32x4*)(Wout + (size_t)j * QD + h * DH + d4 * 4);
#pragma unroll
                for (int u = 0; u < 4; u++)
#pragma unroll
                    for (int t = 0; t < 4; t++)
                        acc[i][t] = fmaf(sv[t][d4 * 4 + u], w[u], acc[i][t]);
            }
        }
#pragma unroll
        for (int i = 0; i < 5; i++) {
            int j = tid + 256 * i;
#pragma unroll
            for (int t = 0; t < 4; t++)
                VW[((size_t)b * OO + h * 4 + t) * QD + j] = acc[i][t];
        }
    }
}

// ---------------------------------------------------------------------------
// K2b: pre-pack P (f32 [b][k][o]) into bf16 MFMA B-fragments.
// Pfrag[b][ks][nt][lane][j] where k = ks*32 + (lane>>4)*8 + j, o = nt*16+(lane&15).
// Pairs (j even, j+1) packed with v_cvt_pk_bf16_f32 — SAME pairing as the
// A-side in scores_kernel, so the dot pairing is lo/hi-convention-invariant.
// grid (80 = ks*2+nt, 16 b), 64 thr.
// ---------------------------------------------------------------------------
__global__ __launch_bounds__(64) void pfrag_kernel(
    const float* __restrict__ P, unsigned* __restrict__ Pfrag)
{
    const int ksnt = blockIdx.x;          // 0..79
    const int b = blockIdx.y;
    const int ks = ksnt >> 1, nt = ksnt & 1;
    const int l = threadIdx.x;
    const int k0 = ks * 32 + (l >> 4) * 8;
    const int o  = nt * 16 + (l & 15);

    const float* Pb = P + ((size_t)b * QD + k0) * OO + o;
    float v[8];
#pragma unroll
    for (int j = 0; j < 8; j++) v[j] = Pb[j * OO];

    unsigned d[4];
#pragma unroll
    for (int i = 0; i < 4; i++)
        asm("v_cvt_pk_bf16_f32 %0, %1, %2" : "=v"(d[i]) : "v"(v[2 * i]), "v"(v[2 * i + 1]));

    unsigned* dst = Pfrag + ((size_t)(b * 80 + ksnt) * 64 + l) * 4;
    dst[0] = d[0]; dst[1] = d[1]; dst[2] = d[2]; dst[3] = d[3];
}

// ---------------------------------------------------------------------------
// K3: scores via bf16 MFMA, k-split x2 (round-7).
//
// Round-7 change: 512-thr blocks; waves 0-3 do k in [0,640), waves 4-7 do
// [640,1280) for the same 64 rows -> 8192 waves = 8 waves/SIMD (HW max),
// halving per-wave exposed VMEM latency vs round-6's 4/SIMD. Cross-half
// reduce through a 9-padded LDS tile (conflict-free), one barrier.
//
// A-frag: lane l -> row (l&15), k = kb + (l>>4)*8 + j  (cvt_pk from f32 x).
// B-frag: pre-packed by pfrag_kernel (same j pairing).
// C: col = lane&15 (=o), row = (lane>>4)*4 + reg   [m89 layout].
//
// grid (64 s-tiles of 64 rows, 16 b), 512 thr.
// ---------------------------------------------------------------------------
__global__ __launch_bounds__(512, 8) void scores_kernel(
    const float* __restrict__ x, const unsigned* __restrict__ Pfrag,
    float* __restrict__ Wgt)
{
    const int b = blockIdx.y;
    const int tid = threadIdx.x;
    const int w = tid >> 6, l = tid & 63;
    const int g = w & 3;              // row group 0..3
    const int khalf = w >> 2;         // k-half 0/1
    const int lg = l >> 4, lo16 = l & 15;
    const int rowbase = blockIdx.x * 64 + g * 16;       // per-batch s of this wave
    const float scale = 0.07905694150420949f;           // 1/sqrt(160)

    __shared__ float red[4][64][9];   // 9-pad -> conflict-free

    f32x4 acc0 = (f32x4){0.f, 0.f, 0.f, 0.f};
    f32x4 acc1 = (f32x4){0.f, 0.f, 0.f, 0.f};

    const float* xr0 = x + ((size_t)b * SS + rowbase + lo16) * QD + khalf * 640;
    const unsigned* Pfb = Pfrag + (size_t)b * 80 * 256 + (size_t)l * 4
                        + (size_t)khalf * 40 * 256;

    union U { unsigned u[4]; short8 s; };

    for (int ks = 0; ks < 20; ++ks) {
        const int kb = ks * 32 + lg * 8;
        f32x4 x00 = *(const f32x4*)(xr0 + kb);
        f32x4 x01 = *(const f32x4*)(xr0 + kb + 4);
        short8 bf0 = *(const short8*)(Pfb + (size_t)(ks * 2 + 0) * 256);
        short8 bf1 = *(const short8*)(Pfb + (size_t)(ks * 2 + 1) * 256);

        U a0;
        asm("v_cvt_pk_bf16_f32 %0, %1, %2" : "=v"(a0.u[0]) : "v"(x00[0]), "v"(x00[1]));
        asm("v_cvt_pk_bf16_f32 %0, %1, %2" : "=v"(a0.u[1]) : "v"(x00[2]), "v"(x00[3]));
        asm("v_cvt_pk_bf16_f32 %0, %1, %2" : "=v"(a0.u[2]) : "v"(x01[0]), "v"(x01[1]));
        asm("v_cvt_pk_bf16_f32 %0, %1, %2" : "=v"(a0.u[3]) : "v"(x01[2]), "v"(x01[3]));

        acc0 = __builtin_amdgcn_mfma_f32_16x16x32_bf16(a0.s, bf0, acc0, 0, 0, 0);
        acc1 = __builtin_amdgcn_mfma_f32_16x16x32_bf16(a0.s, bf1, acc1, 0, 0, 0);
    }

    // cross-khalf reduce: high waves deposit partials, low waves add.
    if (khalf == 1) {
#pragma unroll
        for (int r = 0; r < 4; ++r) {
            red[g][l][r]     = acc0[r];
            red[g][l][4 + r] = acc1[r];
        }
    }
    __syncthreads();
    if (khalf == 1) return;

#pragma unroll
    for (int r = 0; r < 4; ++r) {
        acc0[r] += red[g][l][r];
        acc1[r] += red[g][l][4 + r];
    }

    // epilogue: lane holds rows (rowbase + lg*4 + r) at o = lo16 and lo16+16.
    // z = o&1 = l&1 (same parity for both N-tiles). op0 = (1/8) * sum of the
    // 16 even-o sigmas; reduce across the 16-lane group via shfl_xor (masks
    // 1,2,4,8 stay within the lg group, which owns these 4 rows).
#pragma unroll
    for (int r = 0; r < 4; ++r) {
        float s0v = 1.f / (1.f + __expf(-acc0[r] * scale));
        float s1v = 1.f / (1.f + __expf(-acc1[r] * scale));
        float contrib = ((l & 1) == 0) ? (s0v + s1v) : 0.f;
        contrib += __shfl_xor(contrib, 1);
        contrib += __shfl_xor(contrib, 2);
        contrib += __shfl_xor(contrib, 4);
        contrib += __shfl_xor(contrib, 8);
        float op0 = fminf(contrib * 0.125f, 1.f);
        float t1 = (l & 1) ? (1.f - op0) : 1.f;
        const int R = rowbase + lg * 4 + r;
        float* Wr = Wgt + ((size_t)b * SS + R) * OO;
        Wr[lo16]      = s0v * t1;
        Wr[lo16 + 16] = s1v * t1;
    }
}

// ---------------------------------------------------------------------------
// K4: out[b,s,j] = x[b,s,j] + bout[j] + sum_ht w[b,s,ht] * VW[b,ht,j]
//
// Weights Wgt[row][.] are BLOCK-UNIFORM -> read through a uniform address so
// the compiler emits s_load (SMEM pipe): no LDS, no __syncthreads, no
// broadcast waste. Grid 1024 blocks (4/CU); rows unrolled x2 so two rows'
// x-loads / s_loads are in flight; the 4 components of the f32x4 accumulator
// are independent FMA chains.
//
// grid (64 s-tiles of 64, 16 b), 320 thr (QD/4 float4 chunks, 16B/lane).
// Thread keeps VW[b][*][4*tid..4*tid+3] in 128 VGPRs.
// ---------------------------------------------------------------------------
__global__ __launch_bounds__(320) void out_kernel(
    const float* __restrict__ x, const float* __restrict__ bout,
    const float* __restrict__ VW, const float* __restrict__ Wgt,
    float* __restrict__ out)
{
    const int b = blockIdx.y;
    const int s0 = blockIdx.x * 64;
    const int tid = threadIdx.x;

    f32x4 vw[32];
    {
        const float* VWb = VW + (size_t)b * OO * QD + 4 * tid;
#pragma unroll
        for (int ht = 0; ht < 32; ht++) vw[ht] = *(const f32x4*)(VWb + ht * QD);
    }
    f32x4 bo = *(const f32x4*)(bout + 4 * tid);

    const size_t base = ((size_t)b * SS + s0) * QD + 4 * tid;
    const float* wg0 = Wgt + ((size_t)b * SS + s0) * OO;   // uniform base

#pragma unroll 2
    for (int row = 0; row < 64; ++row) {
        f32x4 acc = bo + *(const f32x4*)(x + base + (size_t)row * QD);
        const float* wr = wg0 + row * OO;                  // uniform -> s_load
#pragma unroll
        for (int ht = 0; ht < 32; ht++) {
            float wv_ = wr[ht];
            acc += wv_ * vw[ht];
        }
        *(f32x4*)(out + base + (size_t)row * QD) = acc;
    }
}

// ---------------------------------------------------------------------------
extern "C" void kernel_launch(void* const* d_in, const int* in_sizes, int n_in,
                              void* d_out, int out_size, void* d_ws, size_t ws_size,
                              hipStream_t stream) {
    const float* x    = (const float*)d_in[0];
    const float* ctx  = (const float*)d_in[1];
    const float* Wq   = (const float*)d_in[2];
    const float* Wk   = (const float*)d_in[3];
    const float* Ak   = (const float*)d_in[4];
    const float* Bk   = (const float*)d_in[5];
    const float* Wv   = (const float*)d_in[6];
    const float* Av   = (const float*)d_in[7];
    const float* Bv   = (const float*)d_in[8];
    const float* pe   = (const float*)d_in[9];
    const float* Wout = (const float*)d_in[10];
    const float* bout = (const float*)d_in[11];
    float* out = (float*)d_out;

    // Workspace layout (floats):
    // Kf 81920 | Vf 81920 | P 655360 | VW 655360 | Wgt 2097152 | Pfrag 327680
    float* ws = (float*)d_ws;
    float* Kf = ws;
    float* Vf = ws + 81920;
    float* P  = ws + 163840;
    float* VW = ws + 819200;
    float* Wg = ws + 1474560;
    unsigned* Pfrag = (unsigned*)(ws + 3571712);   // total 3,899,392 floats = 15.6 MB

    kv_kernel<<<dim3(5, 4, 16), 256, 0, stream>>>(ctx, pe, Wk, Ak, Bk, Wv, Av, Bv, Kf, Vf);
    pvw_kernel<<<dim3(2, 8, 16), 256, 0, stream>>>(Wq, Wout, Kf, Vf, P, VW);
    pfrag_kernel<<<dim3(80, 16), 64, 0, stream>>>(P, Pfrag);
    scores_kernel<<<dim3(64, 16), 512, 0, stream>>>(x, Pfrag, Wg);
    out_kernel<<<dim3(64, 16), 320, 0, stream>>>(x, bout, VW, Wg, out);
}